// Round 9
// baseline (1711.041 us; speedup 1.0000x reference)
//
#include <hip/hip_runtime.h>

#define NPTS 16384
#define DIM 512
#define KCL 512
#define TEMPV 0.1f
#define EPSV 1e-8f
#define MAXIT 100
#define RTOLV 1e-4f
#define ATOLV 1e-8f
#define NSLC 8   // gather slices (fallback path only)

typedef float f32x4 __attribute__((ext_vector_type(4)));
typedef short s16x8 __attribute__((ext_vector_type(8)));

// ---------------- helpers ----------------

__device__ inline float blockReduceSum256(float v) {
    #pragma unroll
    for (int o = 32; o > 0; o >>= 1) v += __shfl_down(v, o, 64);
    __shared__ float wsum[4];
    int lane = threadIdx.x & 63, w = threadIdx.x >> 6;
    if (lane == 0) wsum[w] = v;
    __syncthreads();
    float r = 0.f;
    if (threadIdx.x == 0) r = wsum[0] + wsum[1] + wsum[2] + wsum[3];
    return r;  // valid on thread 0 only
}

__device__ inline unsigned short bf16rne(float v) {
    unsigned u = __float_as_uint(v);
    return (unsigned short)((u + 0x7FFFu + ((u >> 16) & 1u)) >> 16);
}

// iteration `it` is dead if done, or previous iter had no violation
__device__ inline bool iterDead(const unsigned* done, const unsigned* viol, int it) {
    if (*done) return true;
    if (it > 0 && viol[(it - 1) & 1] == 0u) return true;
    return false;
}

// ---------------- init ----------------

__global__ __launch_bounds__(256) void k_init0(const float* __restrict__ x,
                                               const int* __restrict__ idx,
                                               float* __restrict__ c, float* __restrict__ ct,
                                               unsigned short* __restrict__ ch,
                                               unsigned long long* __restrict__ packed0,
                                               unsigned long long* __restrict__ packed1,
                                               unsigned* __restrict__ counts,
                                               unsigned* __restrict__ done,
                                               unsigned* __restrict__ viol,
                                               float* __restrict__ loss, int do_split) {
    int e = blockIdx.x * 256 + threadIdx.x;      // 0 .. K*D-1 (grid = 1024 blocks)
    int j = e >> 9, d = e & 511;
    float v = x[(size_t)idx[j] * DIM + d];
    c[e] = v;
    ct[(size_t)d * KCL + j] = v;
    if (do_split) ch[e] = bf16rne(v);
    if (e < NPTS) { packed0[e] = ~0ull; packed1[e] = ~0ull; }
    if (e < KCL) counts[e] = 0u;
    if (e == 0) { *done = 0u; viol[0] = 0u; viol[1] = 0u; *loss = 0.f; }
}

__global__ __launch_bounds__(256) void k_csq0(const float* __restrict__ c, float* __restrict__ c_sq) {
    int j = blockIdx.x, t = threadIdx.x;
    float a = c[(size_t)j * DIM + t], b = c[(size_t)j * DIM + t + 256];
    float s = blockReduceSum256(a * a + b * b);
    if (t == 0) c_sq[j] = s;
}

// x (static) -> bf16, once. grid = NPTS*DIM/4/256 = 8192
__global__ __launch_bounds__(256) void k_splitx(const float* __restrict__ x,
                                                unsigned short* __restrict__ xh) {
    int e4 = blockIdx.x * 256 + threadIdx.x;
    float4 v = reinterpret_cast<const float4*>(x)[e4];
    ushort4 h;
    h.x = bf16rne(v.x); h.y = bf16rne(v.y); h.z = bf16rne(v.z); h.w = bf16rne(v.w);
    reinterpret_cast<ushort4*>(xh)[e4] = h;
}

// ---------------- assign: bf16 MFMA, superstep-staged B in LDS, fused argmin ----
// grid (4,64): x = col-block (128 cols), y = row-block (256 rows).
// Block 256 thr = 4 waves; wave w owns 64 rows (4 rf) x 128 cols (8 cf).
// B staged in TWO 64KB supersteps (256 k each) -> only 4 barriers total.

__global__ __launch_bounds__(256) void k_assign_mfma(
        const unsigned short* __restrict__ xh,
        const unsigned short* __restrict__ ch,
        const float* __restrict__ csq,
        unsigned long long* __restrict__ packed,
        unsigned* __restrict__ viol,
        unsigned* __restrict__ done, int it) {
    bool lead = (blockIdx.x == 0 && blockIdx.y == 0 && threadIdx.x == 0);
    if (*done) return;
    if (it > 0 && viol[(it - 1) & 1] == 0u) {
        if (lead) *done = 1u;       // latch convergence for all later dispatches
        return;
    }
    if (lead) viol[it & 1] = 0u;    // fresh flag for this iteration's update

    __shared__ unsigned short Bs[32768];     // 64 KB: frag (col, kg) at slot col*32 + (kg^(col&7))

    int tid = threadIdx.x;
    int w = tid >> 6, l = tid & 63;
    int lr = l & 15, lg = l >> 4;
    int row0 = blockIdx.y * 256 + w * 64;
    int col0 = blockIdx.x * 128;

    f32x4 acc[4][8];
    #pragma unroll
    for (int rf = 0; rf < 4; ++rf)
        #pragma unroll
        for (int cf = 0; cf < 8; ++cf) acc[rf][cf] = (f32x4){0.f, 0.f, 0.f, 0.f};

    const unsigned short* ap = xh + (size_t)(row0 + lr) * DIM + 8 * lg;

    #pragma unroll
    for (int s = 0; s < 2; ++s) {
        {   // stage 64KB: 16 frags (16B each) per thread, coalesced source
            int f = tid;
            #pragma unroll
            for (int i = 0; i < 16; ++i, f += 256) {
                int col = f >> 5, kg = f & 31;
                s16x8 v = *(const s16x8*)(ch + (size_t)(col0 + col) * DIM + s * 256 + kg * 8);
                int slot = col * 32 + (kg ^ (col & 7));
                *(s16x8*)&Bs[slot * 8] = v;
            }
        }
        __syncthreads();
        #pragma unroll
        for (int kk = 0; kk < 8; ++kk) {
            int kbase = s * 256 + kk * 32;
            s16x8 a[4];
            #pragma unroll
            for (int rf = 0; rf < 4; ++rf)
                a[rf] = *(const s16x8*)(ap + kbase + (size_t)rf * 16 * DIM);
            #pragma unroll
            for (int cf = 0; cf < 8; ++cf) {
                int col = cf * 16 + lr;
                int slot = col * 32 + ((kk * 4 + lg) ^ (lr & 7));
                s16x8 b = *(const s16x8*)&Bs[slot * 8];
                #pragma unroll
                for (int rf = 0; rf < 4; ++rf)
                    acc[rf][cf] = __builtin_amdgcn_mfma_f32_16x16x32_bf16(a[rf], b, acc[rf][cf], 0, 0, 0);
            }
        }
        __syncthreads();   // drain before next superstep overwrites Bs
    }

    float cs[8];
    #pragma unroll
    for (int cf = 0; cf < 8; ++cf) cs[cf] = csq[col0 + cf * 16 + lr];

    // C/D layout (HW-verified): col = col0+cf*16+lr, row = row0+rf*16+lg*4+r
    #pragma unroll
    for (int rf = 0; rf < 4; ++rf) {
        #pragma unroll
        for (int r = 0; r < 4; ++r) {
            float best = 3.0e38f; int bj = 0;
            #pragma unroll
            for (int cf = 0; cf < 8; ++cf) {
                float v = cs[cf] - 2.0f * acc[rf][cf][r];
                if (v < best) { best = v; bj = col0 + cf * 16 + lr; }
            }
            unsigned u = __float_as_uint(best);
            u ^= ((int)u < 0) ? 0xFFFFFFFFu : 0x80000000u;  // sortable-float map
            unsigned long long key = ((unsigned long long)u << 32) | (unsigned)bj;
            #pragma unroll
            for (int m = 1; m <= 8; m <<= 1) {
                unsigned long long o = __shfl_xor(key, m, 64);
                key = (o < key) ? o : key;
            }
            if (lr == 0) atomicMin(&packed[row0 + rf * 16 + lg * 4 + r], key);
        }
    }
}

// ---------------- fused gather+update: one block per cluster ----------------
// grid KCL, block 256. Block j scans ALL ids (32 pipelined uint4 chunks = 2
// packed entries/thread/chunk), sums matching bf16 rows in registers (thread t
// owns dims 2t,2t+1), then commits: conv check, c/ch/c_sq, ids, and re-arms
// the OTHER packed buffer (double-buffered -> no race with other scanners).

__global__ __launch_bounds__(256) void k_gatherupd(
        const unsigned long long* __restrict__ packed,
        unsigned long long* __restrict__ packed_next,
        const unsigned short* __restrict__ xh,
        float* __restrict__ c, float* __restrict__ c_sq,
        unsigned short* __restrict__ ch, int* __restrict__ ids,
        unsigned* __restrict__ viol, const unsigned* __restrict__ done, int it) {
    if (iterDead(done, viol, it)) return;
    int j = blockIdx.x, t = threadIdx.x;
    const uint4* pk4 = (const uint4*)packed;          // entries 2k,2k+1 per uint4
    const unsigned* xr32 = (const unsigned*)xh;       // row i at xr32 + i*256

    __shared__ int list[512];
    __shared__ int lcnt;

    float a0 = 0.f, a1 = 0.f;
    int cnt = 0;
    uint4 cur = pk4[t];                               // prefetch chunk 0
    for (int chn = 0; chn < 32; ++chn) {
        uint4 nxt;
        if (chn < 31) nxt = pk4[(chn + 1) * 256 + t]; // issue-early (hide L2 latency)
        if (t == 0) lcnt = 0;
        __syncthreads();                              // lcnt reset + prev processing done
        int i0 = chn * 512 + 2 * t;
        if (cur.x == (unsigned)j) list[atomicAdd(&lcnt, 1)] = i0;
        if (cur.z == (unsigned)j) list[atomicAdd(&lcnt, 1)] = i0 + 1;
        __syncthreads();                              // compaction done
        int n = lcnt;
        for (int p = 0; p < n; ++p) {
            unsigned u = xr32[(size_t)list[p] * 256 + t];  // bf16 pair: dims 2t,2t+1
            a0 += __uint_as_float(u << 16);
            a1 += __uint_as_float(u & 0xffff0000u);
        }
        cnt += n;
        cur = nxt;
    }

    float cf = fmaxf((float)cnt, 1.f);
    float n0 = a0 / cf, n1 = a1 / cf;
    float2 cc = ((const float2*)(c + (size_t)j * DIM))[t];
    bool bad = !((fabsf(cc.x - n0) <= ATOLV + RTOLV * fabsf(n0)) &&
                 (fabsf(cc.y - n1) <= ATOLV + RTOLV * fabsf(n1)));
    unsigned long long bm = __ballot(bad);
    if ((t & 63) == 0 && bm) atomicOr(&viol[it & 1], 1u);
    ((float2*)(c + (size_t)j * DIM))[t] = make_float2(n0, n1);   // commit
    ((unsigned*)(ch + (size_t)j * DIM))[t] =
        (unsigned)bf16rne(n0) | ((unsigned)bf16rne(n1) << 16);
    float ss = blockReduceSum256(n0 * n0 + n1 * n1);
    if (t == 0) c_sq[j] = ss;
    if (t < 32) {                    // ids + re-arm NEXT buffer for rows [32j,32j+32)
        int i = j * 32 + t;
        ids[i] = (int)(unsigned)(packed[i] & 0xffffffffull);
        packed_next[i] = ~0ull;
    }
}

// ---------------- loss phase (MFMA path) ----------------

__global__ __launch_bounds__(256) void k_invx(const float* __restrict__ x, float* __restrict__ invx) {
    int r = blockIdx.x, t = threadIdx.x;
    float a = x[(size_t)r * DIM + t], b = x[(size_t)r * DIM + t + 256];
    float s = blockReduceSum256(a * a + b * b);
    if (t == 0) invx[r] = 1.f / ((sqrtf(s) + EPSV) * (TEMPV + EPSV));
}

__global__ __launch_bounds__(256) void k_cn(const float* __restrict__ src, float* __restrict__ cn,
                                            unsigned short* __restrict__ cnh, int do_split) {
    int j = blockIdx.x, t = threadIdx.x;
    float a = src[(size_t)j * DIM + t], b = src[(size_t)j * DIM + t + 256];
    float s = blockReduceSum256(a * a + b * b);
    __shared__ float bc;
    if (t == 0) bc = 1.f / (sqrtf(s) + EPSV);
    __syncthreads();
    float v0 = a * bc, v1 = b * bc;
    cn[(size_t)j * DIM + t] = v0;
    cn[(size_t)j * DIM + t + 256] = v1;
    if (do_split) {
        cnh[(size_t)j * DIM + t] = bf16rne(v0);
        cnh[(size_t)j * DIM + t + 256] = bf16rne(v1);
    }
}

// bf16 MFMA logits with fused per-row (max, expsum) partials per col-block.
__global__ __launch_bounds__(256) void k_logits_mfma(
        const unsigned short* __restrict__ xh,
        const unsigned short* __restrict__ cnh,
        const float* __restrict__ invx,
        float* __restrict__ pmax, float* __restrict__ psum) {
    int tid = threadIdx.x;
    int w = tid >> 6, l = tid & 63;
    int lr = l & 15, lg = l >> 4;
    int row0 = blockIdx.y * 128 + w * 32;
    int col0 = blockIdx.x * 128;
    int jb = blockIdx.x;

    f32x4 acc[2][8];
    #pragma unroll
    for (int rf = 0; rf < 2; ++rf)
        #pragma unroll
        for (int cf = 0; cf < 8; ++cf) acc[rf][cf] = (f32x4){0.f, 0.f, 0.f, 0.f};

    const unsigned short* a0p = xh + (size_t)(row0 + lr) * DIM + 8 * lg;
    const unsigned short* a1p = a0p + (size_t)16 * DIM;
    const unsigned short* bp  = cnh + (size_t)(col0 + lr) * DIM + 8 * lg;

    #pragma unroll 2
    for (int k0 = 0; k0 < DIM; k0 += 32) {
        s16x8 a0 = *reinterpret_cast<const s16x8*>(a0p + k0);
        s16x8 a1 = *reinterpret_cast<const s16x8*>(a1p + k0);
        #pragma unroll
        for (int cf = 0; cf < 8; ++cf) {
            s16x8 b = *reinterpret_cast<const s16x8*>(bp + (size_t)cf * 16 * DIM + k0);
            acc[0][cf] = __builtin_amdgcn_mfma_f32_16x16x32_bf16(a0, b, acc[0][cf], 0, 0, 0);
            acc[1][cf] = __builtin_amdgcn_mfma_f32_16x16x32_bf16(a1, b, acc[1][cf], 0, 0, 0);
        }
    }

    #pragma unroll
    for (int rf = 0; rf < 2; ++rf) {
        #pragma unroll
        for (int r = 0; r < 4; ++r) {
            int row = row0 + rf * 16 + lg * 4 + r;
            float inv = invx[row];
            float m = -3.0e38f;
            #pragma unroll
            for (int cf = 0; cf < 8; ++cf) m = fmaxf(m, acc[rf][cf][r] * inv);
            #pragma unroll
            for (int msk = 1; msk <= 8; msk <<= 1) m = fmaxf(m, __shfl_xor(m, msk, 64));
            float s = 0.f;
            #pragma unroll
            for (int cf = 0; cf < 8; ++cf) s += expf(acc[rf][cf][r] * inv - m);
            #pragma unroll
            for (int msk = 1; msk <= 8; msk <<= 1) s += __shfl_xor(s, msk, 64);
            if (lr == 0) {
                pmax[(size_t)row * 4 + jb] = m;
                psum[(size_t)row * 4 + jb] = s;
            }
        }
    }
}

__global__ __launch_bounds__(256) void k_loss(const float* __restrict__ x,
                                              const float* __restrict__ cn,
                                              const int* __restrict__ ids,
                                              const float* __restrict__ invx,
                                              const float* __restrict__ pmax,
                                              const float* __restrict__ psum,
                                              float* __restrict__ loss) {
    int i = blockIdx.x * 256 + threadIdx.x;
    float M = -1e30f;
    #pragma unroll
    for (int b = 0; b < 4; ++b) M = fmaxf(M, pmax[(size_t)i * 4 + b]);
    float S = 0.f;
    #pragma unroll
    for (int b = 0; b < 4; ++b) S += psum[(size_t)i * 4 + b] * expf(pmax[(size_t)i * 4 + b] - M);
    float lse = M + logf(S);
    int j = ids[i];
    const float4* xr = (const float4*)(x + (size_t)i * DIM);
    const float4* cr = (const float4*)(cn + (size_t)j * DIM);
    float dot = 0.f;
    for (int q = 0; q < 128; ++q) {
        float4 a = xr[q], b = cr[q];
        dot += a.x * b.x + a.y * b.y + a.z * b.z + a.w * b.w;
    }
    float t = dot * invx[i];
    float contrib = lse - t;
    float s = blockReduceSum256(contrib);
    if (threadIdx.x == 0) atomicAdd(loss, s);
}

__global__ void k_final(const float* __restrict__ loss, float* __restrict__ out) {
    out[0] = *loss / (float)NPTS;
}

// ---------------- fallback fp32 path (ws too small) ----------------

__global__ __launch_bounds__(256) void k_assign(const float* __restrict__ x,
                                                const float* __restrict__ ct,
                                                const float* __restrict__ csq,
                                                unsigned long long* __restrict__ packed,
                                                const unsigned* __restrict__ done) {
    if (*done) return;
    __shared__ float As[16][128];
    __shared__ float Bs[16][128];
    __shared__ float redv[128][17];
    __shared__ int   redj[128][17];

    int tid = threadIdx.x;
    int ty = tid >> 4, tx = tid & 15;
    int row0 = blockIdx.x * 128, col0 = blockIdx.y * 128;

    float acc[8][8];
    #pragma unroll
    for (int i = 0; i < 8; ++i)
        #pragma unroll
        for (int j = 0; j < 8; ++j) acc[i][j] = 0.f;

    for (int dk = 0; dk < DIM; dk += 16) {
        {
            int r = tid >> 1;
            int d0 = (tid & 1) * 8;
            const float4* src = reinterpret_cast<const float4*>(&x[(size_t)(row0 + r) * DIM + dk + d0]);
            float4 v0 = src[0], v1 = src[1];
            As[d0 + 0][r] = v0.x; As[d0 + 1][r] = v0.y; As[d0 + 2][r] = v0.z; As[d0 + 3][r] = v0.w;
            As[d0 + 4][r] = v1.x; As[d0 + 5][r] = v1.y; As[d0 + 6][r] = v1.z; As[d0 + 7][r] = v1.w;
        }
        {
            int d = tid >> 4;
            int c0 = (tid & 15) * 8;
            const float4* src = reinterpret_cast<const float4*>(&ct[(size_t)(dk + d) * KCL + col0 + c0]);
            float4 v0 = src[0], v1 = src[1];
            *reinterpret_cast<float4*>(&Bs[d][c0]) = v0;
            *reinterpret_cast<float4*>(&Bs[d][c0 + 4]) = v1;
        }
        __syncthreads();
        #pragma unroll
        for (int kk = 0; kk < 16; ++kk) {
            float a[8], b[8];
            *(float4*)&a[0] = *(const float4*)&As[kk][ty * 8];
            *(float4*)&a[4] = *(const float4*)&As[kk][ty * 8 + 4];
            *(float4*)&b[0] = *(const float4*)&Bs[kk][tx * 8];
            *(float4*)&b[4] = *(const float4*)&Bs[kk][tx * 8 + 4];
            #pragma unroll
            for (int i = 0; i < 8; ++i)
                #pragma unroll
                for (int j = 0; j < 8; ++j) acc[i][j] = fmaf(a[i], b[j], acc[i][j]);
        }
        __syncthreads();
    }

    #pragma unroll
    for (int i = 0; i < 8; ++i) {
        float best = 1e30f; int bj = col0 + tx * 8;
        #pragma unroll
        for (int j = 0; j < 8; ++j) {
            int col = col0 + tx * 8 + j;
            float v = csq[col] - 2.f * acc[i][j];
            if (v < best) { best = v; bj = col; }
        }
        redv[ty * 8 + i][tx] = best;
        redj[ty * 8 + i][tx] = bj;
    }
    __syncthreads();
    if (tid < 128) {
        float best = 1e30f; int bj = 0x7fffffff;
        for (int t2 = 0; t2 < 16; ++t2) {
            float v = redv[tid][t2]; int j = redj[tid][t2];
            if (v < best || (v == best && j < bj)) { best = v; bj = j; }
        }
        unsigned u = __float_as_uint(best);
        u ^= (u >> 31) ? 0xFFFFFFFFu : 0x80000000u;
        unsigned long long key = ((unsigned long long)u << 32) | (unsigned)bj;
        atomicMin(&packed[row0 + tid], key);
    }
}

__global__ __launch_bounds__(256) void k_hist(const unsigned long long* __restrict__ packed,
                                              int* __restrict__ ids, unsigned* __restrict__ counts,
                                              const unsigned* __restrict__ done) {
    if (*done) return;
    int i = blockIdx.x * 256 + threadIdx.x;
    unsigned long long p = packed[i];
    int j = (int)(unsigned)(p & 0xffffffffull);
    ids[i] = j;
    atomicAdd(&counts[j], 1u);
}

__global__ void k_scan(const unsigned* __restrict__ counts, unsigned* __restrict__ offsets,
                       unsigned* __restrict__ cursors, const unsigned* __restrict__ done) {
    if (*done) return;
    __shared__ unsigned s[512];
    int t = threadIdx.x;
    unsigned c0 = counts[t];
    s[t] = c0;
    __syncthreads();
    for (int off = 1; off < 512; off <<= 1) {
        unsigned v = (t >= off) ? s[t - off] : 0u;
        __syncthreads();
        s[t] += v;
        __syncthreads();
    }
    unsigned excl = s[t] - c0;
    offsets[t] = excl;
    cursors[t] = excl;
}

__global__ __launch_bounds__(256) void k_scatter(const int* __restrict__ ids,
                                                 unsigned* __restrict__ cursors,
                                                 int* __restrict__ order,
                                                 const unsigned* __restrict__ done) {
    if (*done) return;
    int i = blockIdx.x * 256 + threadIdx.x;
    int j = ids[i];
    unsigned pos = atomicAdd(&cursors[j], 1u);
    order[pos] = i;
}

__global__ __launch_bounds__(256) void k_sumconv(const float* __restrict__ x,
                                                 const int* __restrict__ order,
                                                 const unsigned* __restrict__ offsets,
                                                 const unsigned* __restrict__ counts,
                                                 const float* __restrict__ c,
                                                 float* __restrict__ new_c,
                                                 unsigned* __restrict__ viol,
                                                 const unsigned* __restrict__ done, int it) {
    if (*done) return;
    int j = blockIdx.x, t = threadIdx.x;
    unsigned cnt = counts[j], base = offsets[j];
    float a0 = 0.f, a1 = 0.f;
    for (unsigned p = 0; p < cnt; ++p) {
        int i = order[base + p];
        const float* xr = x + (size_t)i * DIM;
        a0 += xr[t]; a1 += xr[t + 256];
    }
    float cf = fmaxf((float)cnt, 1.f);
    float n0 = a0 / cf, n1 = a1 / cf;
    new_c[(size_t)j * DIM + t] = n0;
    new_c[(size_t)j * DIM + t + 256] = n1;
    float c0 = c[(size_t)j * DIM + t], c1 = c[(size_t)j * DIM + t + 256];
    bool ok = (fabsf(c0 - n0) <= ATOLV + RTOLV * fabsf(n0)) &&
              (fabsf(c1 - n1) <= ATOLV + RTOLV * fabsf(n1));
    unsigned long long bad = __ballot(!ok);
    if ((t & 63) == 0 && bad) atomicOr(&viol[it & 1], 1u);
}

__global__ __launch_bounds__(256) void k_commit(float* __restrict__ c, const float* __restrict__ new_c,
                                                float* __restrict__ c_sq,
                                                unsigned long long* __restrict__ packed,
                                                unsigned* __restrict__ counts,
                                                unsigned* __restrict__ viol,
                                                unsigned* __restrict__ done, int it) {
    if (*done) return;
    unsigned v = viol[it & 1];
    int b = blockIdx.x, t = threadIdx.x;
    int e = b * 256 + t;
    if (v) {
        float n0 = new_c[(size_t)b * DIM + t], n1 = new_c[(size_t)b * DIM + t + 256];
        c[(size_t)b * DIM + t] = n0;
        c[(size_t)b * DIM + t + 256] = n1;
        float s = blockReduceSum256(n0 * n0 + n1 * n1);
        if (t == 0) c_sq[b] = s;
    } else {
        if (e == 0) *done = 1u;
    }
    if (e < NPTS) packed[e] = ~0ull;
    if (e < KCL) counts[e] = 0u;
    if (e == 0) viol[(it + 1) & 1] = 0u;
}

__global__ void k_trans(const float* __restrict__ src, float* __restrict__ dst,
                        const unsigned* __restrict__ done, int check) {
    if (check && *done) return;
    __shared__ float tile[32][33];
    int bx = blockIdx.x & 15, by = blockIdx.x >> 4;
    int tx = threadIdx.x & 31, ty = threadIdx.x >> 5;
    #pragma unroll
    for (int q = 0; q < 4; ++q) {
        int r = by * 32 + ty + q * 8;
        tile[ty + q * 8][tx] = src[(size_t)r * DIM + bx * 32 + tx];
    }
    __syncthreads();
    #pragma unroll
    for (int q = 0; q < 4; ++q) {
        int d = bx * 32 + ty + q * 8;
        dst[(size_t)d * KCL + by * 32 + tx] = tile[tx][ty + q * 8];
    }
}

__global__ __launch_bounds__(256) void k_logits(const float* __restrict__ x,
                                                const float* __restrict__ ct,
                                                const float* __restrict__ invx,
                                                float* __restrict__ pmax, float* __restrict__ psum) {
    __shared__ float As[16][128];
    __shared__ float Bs[16][128];
    __shared__ float red2[128][17];
    __shared__ float rowm[128];

    int tid = threadIdx.x;
    int ty = tid >> 4, tx = tid & 15;
    int row0 = blockIdx.x * 128, col0 = blockIdx.y * 128;
    int jb = blockIdx.y;

    float acc[8][8];
    #pragma unroll
    for (int i = 0; i < 8; ++i)
        #pragma unroll
        for (int j = 0; j < 8; ++j) acc[i][j] = 0.f;

    for (int dk = 0; dk < DIM; dk += 16) {
        {
            int r = tid >> 1;
            int d0 = (tid & 1) * 8;
            const float4* src = reinterpret_cast<const float4*>(&x[(size_t)(row0 + r) * DIM + dk + d0]);
            float4 v0 = src[0], v1 = src[1];
            As[d0 + 0][r] = v0.x; As[d0 + 1][r] = v0.y; As[d0 + 2][r] = v0.z; As[d0 + 3][r] = v0.w;
            As[d0 + 4][r] = v1.x; As[d0 + 5][r] = v1.y; As[d0 + 6][r] = v1.z; As[d0 + 7][r] = v1.w;
        }
        {
            int d = tid >> 4;
            int c0 = (tid & 15) * 8;
            const float4* src = reinterpret_cast<const float4*>(&ct[(size_t)(dk + d) * KCL + col0 + c0]);
            float4 v0 = src[0], v1 = src[1];
            *reinterpret_cast<float4*>(&Bs[d][c0]) = v0;
            *reinterpret_cast<float4*>(&Bs[d][c0 + 4]) = v1;
        }
        __syncthreads();
        #pragma unroll
        for (int kk = 0; kk < 16; ++kk) {
            float a[8], b[8];
            *(float4*)&a[0] = *(const float4*)&As[kk][ty * 8];
            *(float4*)&a[4] = *(const float4*)&As[kk][ty * 8 + 4];
            *(float4*)&b[0] = *(const float4*)&Bs[kk][tx * 8];
            *(float4*)&b[4] = *(const float4*)&Bs[kk][tx * 8 + 4];
            #pragma unroll
            for (int i = 0; i < 8; ++i)
                #pragma unroll
                for (int j = 0; j < 8; ++j) acc[i][j] = fmaf(a[i], b[j], acc[i][j]);
        }
        __syncthreads();
    }

    float inv[8];
    #pragma unroll
    for (int i = 0; i < 8; ++i) inv[i] = invx[row0 + ty * 8 + i];

    #pragma unroll
    for (int i = 0; i < 8; ++i) {
        float m = -1e30f;
        #pragma unroll
        for (int j = 0; j < 8; ++j) m = fmaxf(m, acc[i][j] * inv[i]);
        red2[ty * 8 + i][tx] = m;
    }
    __syncthreads();
    if (tid < 128) {
        float m = -1e30f;
        for (int t2 = 0; t2 < 16; ++t2) m = fmaxf(m, red2[tid][t2]);
        rowm[tid] = m;
    }
    __syncthreads();
    #pragma unroll
    for (int i = 0; i < 8; ++i) {
        float M = rowm[ty * 8 + i];
        float s = 0.f;
        #pragma unroll
        for (int j = 0; j < 8; ++j) s += expf(acc[i][j] * inv[i] - M);
        red2[ty * 8 + i][tx] = s;
    }
    __syncthreads();
    if (tid < 128) {
        float s = 0.f;
        for (int t2 = 0; t2 < 16; ++t2) s += red2[tid][t2];
        pmax[(size_t)(row0 + tid) * 4 + jb] = rowm[tid];
        psum[(size_t)(row0 + tid) * 4 + jb] = s;
    }
}

// ---------------- launch ----------------

extern "C" void kernel_launch(void* const* d_in, const int* in_sizes, int n_in,
                              void* d_out, int out_size, void* d_ws, size_t ws_size,
                              hipStream_t stream) {
    const float* x = (const float*)d_in[0];
    const int* init_idx = (const int*)d_in[1];
    float* out = (float*)d_out;

    char* w = (char*)d_ws;
    float* c      = (float*)w; w += (size_t)KCL * DIM * 4;
    float* new_c  = (float*)w; w += (size_t)KCL * DIM * 4;
    float* ct     = (float*)w; w += (size_t)DIM * KCL * 4;
    float* c_sq   = (float*)w; w += KCL * 4;
    unsigned* counts  = (unsigned*)w; w += KCL * 4;
    unsigned* offsets = (unsigned*)w; w += KCL * 4;
    unsigned* cursors = (unsigned*)w; w += KCL * 4;
    unsigned* done = (unsigned*)w; w += 64;
    unsigned* viol = (unsigned*)w; w += 64;
    float* loss    = (float*)w; w += 64;
    int* ids   = (int*)w; w += NPTS * 4;
    int* order = (int*)w; w += NPTS * 4;
    unsigned long long* packed0 = (unsigned long long*)w; w += NPTS * 8;
    unsigned long long* packed1 = (unsigned long long*)w; w += NPTS * 8;
    float* invx = (float*)w; w += NPTS * 4;
    float* pmax = (float*)w; w += (size_t)NPTS * 4 * 4;
    float* psum = (float*)w; w += (size_t)NPTS * 4 * 4;
    unsigned short* ch = (unsigned short*)w; w += (size_t)KCL * DIM * 2;
    unsigned short* cnh = (unsigned short*)w; w += (size_t)KCL * DIM * 2;
    unsigned short* xh = (unsigned short*)w; w += (size_t)NPTS * DIM * 2;
    size_t need = (size_t)(w - (char*)d_ws);
    int use_mfma = (ws_size >= need) ? 1 : 0;

    k_init0<<<1024, 256, 0, stream>>>(x, init_idx, c, ct, ch, packed0,
                                      use_mfma ? packed1 : packed0,
                                      counts, done, viol, loss, use_mfma);
    k_csq0<<<KCL, 256, 0, stream>>>(c, c_sq);
    if (use_mfma)
        k_splitx<<<NPTS * DIM / 4 / 256, 256, 0, stream>>>(x, xh);

    for (int it = 0; it < MAXIT; ++it) {
        if (use_mfma) {
            unsigned long long* pc = (it & 1) ? packed1 : packed0;
            unsigned long long* pn = (it & 1) ? packed0 : packed1;
            k_assign_mfma<<<dim3(4, 64), 256, 0, stream>>>(xh, ch, c_sq, pc, viol, done, it);
            k_gatherupd<<<KCL, 256, 0, stream>>>(pc, pn, xh, c, c_sq, ch, ids, viol, done, it);
        } else {
            k_assign<<<dim3(128, 4), 256, 0, stream>>>(x, ct, c_sq, packed0, done);
            k_hist<<<64, 256, 0, stream>>>(packed0, ids, counts, done);
            k_scan<<<1, 512, 0, stream>>>(counts, offsets, cursors, done);
            k_scatter<<<64, 256, 0, stream>>>(ids, cursors, order, done);
            k_sumconv<<<KCL, 256, 0, stream>>>(x, order, offsets, counts, c, new_c, viol, done, it);
            k_commit<<<KCL, 256, 0, stream>>>(c, new_c, c_sq, packed0, counts, viol, done, it);
            k_trans<<<256, 256, 0, stream>>>(new_c, ct, done, 1);
        }
    }

    // loss phase: centers live in c (mfma path) / new_c (fallback)
    k_invx<<<NPTS, 256, 0, stream>>>(x, invx);
    if (use_mfma) {
        k_cn<<<KCL, 256, 0, stream>>>(c, c, cnh, 1);      // in-place normalize c -> cn
        k_logits_mfma<<<dim3(4, 128), 256, 0, stream>>>(xh, cnh, invx, pmax, psum);
    } else {
        k_cn<<<KCL, 256, 0, stream>>>(new_c, c, cnh, 0);
        k_trans<<<256, 256, 0, stream>>>(c, ct, done, 0);
        k_logits<<<dim3(128, 4), 256, 0, stream>>>(x, ct, invx, pmax, psum);
    }
    k_loss<<<64, 256, 0, stream>>>(x, c, ids, invx, pmax, psum, loss);
    k_final<<<1, 1, 0, stream>>>(loss, out);
}

// Round 10
// 1165.966 us; speedup vs baseline: 1.4675x; 1.4675x over previous
//
#include <hip/hip_runtime.h>

#define NPTS 16384
#define DIM 512
#define KCL 512
#define TEMPV 0.1f
#define EPSV 1e-8f
#define MAXIT 100
#define RTOLV 1e-4f
#define ATOLV 1e-8f
#define NSLC 8   // gather slices per cluster

typedef float f32x4 __attribute__((ext_vector_type(4)));
typedef short s16x8 __attribute__((ext_vector_type(8)));

// ---------------- helpers ----------------

__device__ inline float blockReduceSum256(float v) {
    #pragma unroll
    for (int o = 32; o > 0; o >>= 1) v += __shfl_down(v, o, 64);
    __shared__ float wsum[4];
    int lane = threadIdx.x & 63, w = threadIdx.x >> 6;
    if (lane == 0) wsum[w] = v;
    __syncthreads();
    float r = 0.f;
    if (threadIdx.x == 0) r = wsum[0] + wsum[1] + wsum[2] + wsum[3];
    return r;  // valid on thread 0 only
}

__device__ inline unsigned short bf16rne(float v) {
    unsigned u = __float_as_uint(v);
    return (unsigned short)((u + 0x7FFFu + ((u >> 16) & 1u)) >> 16);
}

// iteration `it` is dead if done, or previous iter had no violation
__device__ inline bool iterDead(const unsigned* done, const unsigned* viol, int it) {
    if (*done) return true;
    if (it > 0 && viol[(it - 1) & 1] == 0u) return true;
    return false;
}

// ---------------- init ----------------

__global__ __launch_bounds__(256) void k_init0(const float* __restrict__ x,
                                               const int* __restrict__ idx,
                                               float* __restrict__ c, float* __restrict__ ct,
                                               unsigned short* __restrict__ ch,
                                               unsigned long long* __restrict__ packed,
                                               unsigned* __restrict__ counts,
                                               unsigned* __restrict__ done,
                                               unsigned* __restrict__ viol,
                                               float* __restrict__ loss, int do_split) {
    int e = blockIdx.x * 256 + threadIdx.x;      // 0 .. K*D-1 (grid = 1024 blocks)
    int j = e >> 9, d = e & 511;
    float v = x[(size_t)idx[j] * DIM + d];
    c[e] = v;
    ct[(size_t)d * KCL + j] = v;
    if (do_split) ch[e] = bf16rne(v);
    if (e < NPTS) packed[e] = ~0ull;
    if (e < KCL) counts[e] = 0u;
    if (e == 0) { *done = 0u; viol[0] = 0u; viol[1] = 0u; *loss = 0.f; }
}

__global__ __launch_bounds__(256) void k_csq0(const float* __restrict__ c, float* __restrict__ c_sq) {
    int j = blockIdx.x, t = threadIdx.x;
    float a = c[(size_t)j * DIM + t], b = c[(size_t)j * DIM + t + 256];
    float s = blockReduceSum256(a * a + b * b);
    if (t == 0) c_sq[j] = s;
}

// x (static) -> bf16, once. grid = NPTS*DIM/4/256 = 8192
__global__ __launch_bounds__(256) void k_splitx(const float* __restrict__ x,
                                                unsigned short* __restrict__ xh) {
    int e4 = blockIdx.x * 256 + threadIdx.x;
    float4 v = reinterpret_cast<const float4*>(x)[e4];
    ushort4 h;
    h.x = bf16rne(v.x); h.y = bf16rne(v.y); h.z = bf16rne(v.z); h.w = bf16rne(v.w);
    reinterpret_cast<ushort4*>(xh)[e4] = h;
}

// ---------------- assign: bf16 MFMA, superstep-staged B in LDS, fused argmin ----
// grid (4,64): x = col-block (128 cols), y = row-block (256 rows).
// Block 256 thr = 4 waves; wave w owns 64 rows (4 rf) x 128 cols (8 cf).
// B staged in TWO 64KB supersteps (256 k each) -> only 4 barriers total.

__global__ __launch_bounds__(256) void k_assign_mfma(
        const unsigned short* __restrict__ xh,
        const unsigned short* __restrict__ ch,
        const float* __restrict__ csq,
        unsigned long long* __restrict__ packed,
        unsigned* __restrict__ viol,
        unsigned* __restrict__ done, int it) {
    bool lead = (blockIdx.x == 0 && blockIdx.y == 0 && threadIdx.x == 0);
    if (*done) return;
    if (it > 0 && viol[(it - 1) & 1] == 0u) {
        if (lead) *done = 1u;       // latch convergence for all later dispatches
        return;
    }
    if (lead) viol[it & 1] = 0u;    // fresh flag for this iteration's update

    __shared__ unsigned short Bs[32768];     // 64 KB: frag (col, kg) at slot col*32 + (kg^(col&7))

    int tid = threadIdx.x;
    int w = tid >> 6, l = tid & 63;
    int lr = l & 15, lg = l >> 4;
    int row0 = blockIdx.y * 256 + w * 64;
    int col0 = blockIdx.x * 128;

    f32x4 acc[4][8];
    #pragma unroll
    for (int rf = 0; rf < 4; ++rf)
        #pragma unroll
        for (int cf = 0; cf < 8; ++cf) acc[rf][cf] = (f32x4){0.f, 0.f, 0.f, 0.f};

    const unsigned short* ap = xh + (size_t)(row0 + lr) * DIM + 8 * lg;

    #pragma unroll
    for (int s = 0; s < 2; ++s) {
        {   // stage 64KB: 16 frags (16B each) per thread, coalesced source
            int f = tid;
            #pragma unroll
            for (int i = 0; i < 16; ++i, f += 256) {
                int col = f >> 5, kg = f & 31;
                s16x8 v = *(const s16x8*)(ch + (size_t)(col0 + col) * DIM + s * 256 + kg * 8);
                int slot = col * 32 + (kg ^ (col & 7));
                *(s16x8*)&Bs[slot * 8] = v;
            }
        }
        __syncthreads();
        #pragma unroll
        for (int kk = 0; kk < 8; ++kk) {
            int kbase = s * 256 + kk * 32;
            s16x8 a[4];
            #pragma unroll
            for (int rf = 0; rf < 4; ++rf)
                a[rf] = *(const s16x8*)(ap + kbase + (size_t)rf * 16 * DIM);
            #pragma unroll
            for (int cf = 0; cf < 8; ++cf) {
                int col = cf * 16 + lr;
                int slot = col * 32 + ((kk * 4 + lg) ^ (lr & 7));
                s16x8 b = *(const s16x8*)&Bs[slot * 8];
                #pragma unroll
                for (int rf = 0; rf < 4; ++rf)
                    acc[rf][cf] = __builtin_amdgcn_mfma_f32_16x16x32_bf16(a[rf], b, acc[rf][cf], 0, 0, 0);
            }
        }
        __syncthreads();   // drain before next superstep overwrites Bs
    }

    float cs[8];
    #pragma unroll
    for (int cf = 0; cf < 8; ++cf) cs[cf] = csq[col0 + cf * 16 + lr];

    // C/D layout (HW-verified): col = col0+cf*16+lr, row = row0+rf*16+lg*4+r
    #pragma unroll
    for (int rf = 0; rf < 4; ++rf) {
        #pragma unroll
        for (int r = 0; r < 4; ++r) {
            float best = 3.0e38f; int bj = 0;
            #pragma unroll
            for (int cf = 0; cf < 8; ++cf) {
                float v = cs[cf] - 2.0f * acc[rf][cf][r];
                if (v < best) { best = v; bj = col0 + cf * 16 + lr; }
            }
            unsigned u = __float_as_uint(best);
            u ^= ((int)u < 0) ? 0xFFFFFFFFu : 0x80000000u;  // sortable-float map
            unsigned long long key = ((unsigned long long)u << 32) | (unsigned)bj;
            #pragma unroll
            for (int m = 1; m <= 8; m <<= 1) {
                unsigned long long o = __shfl_xor(key, m, 64);
                key = (o < key) ? o : key;
            }
            if (lr == 0) atomicMin(&packed[row0 + rf * 16 + lg * 4 + r], key);
        }
    }
}

// ---------------- gather: sliced segment-sum, single-burst scan ----------------
// grid (KCL, NSLC), block 256. Block (j,s) scans its 2048-entry slice in ONE
// burst (8 independent id loads -> one compaction -> 2 barriers total), then
// sums matching bf16 rows (thread t owns dims 2t,2t+1) into its EXCLUSIVE
// partial gsum[s][j][*]. Visibility to k_update via kernel-launch boundary.

__global__ __launch_bounds__(256) void k_gather(
        const unsigned long long* __restrict__ packed,
        const unsigned short* __restrict__ xh,
        float* __restrict__ gsum, unsigned* __restrict__ gcnt,
        const unsigned* __restrict__ viol, const unsigned* __restrict__ done, int it) {
    if (iterDead(done, viol, it)) return;
    int j = blockIdx.x, s = blockIdx.y, t = threadIdx.x;
    const unsigned* pid = (const unsigned*)packed;   // low word of each entry = id
    const unsigned* xr32 = (const unsigned*)xh;      // row i at xr32 + i*256

    __shared__ int list[2048];                       // a slice is exactly 2048 entries
    __shared__ int lcnt;
    if (t == 0) lcnt = 0;
    __syncthreads();

    int base0 = s * (NPTS / NSLC);
    int idv[8];
    #pragma unroll
    for (int q = 0; q < 8; ++q)                      // 8 independent loads (full MLP)
        idv[q] = (int)pid[2 * (base0 + q * 256 + t)];
    #pragma unroll
    for (int q = 0; q < 8; ++q)
        if (idv[q] == j) list[atomicAdd(&lcnt, 1)] = base0 + q * 256 + t;
    __syncthreads();

    int n = lcnt;
    float a0 = 0.f, a1 = 0.f;
    for (int p = 0; p < n; ++p) {
        unsigned u = xr32[(size_t)list[p] * 256 + t];   // bf16 pair: dims 2t, 2t+1
        a0 += __uint_as_float(u << 16);
        a1 += __uint_as_float(u & 0xffff0000u);
    }
    float2* dst = (float2*)(gsum + ((size_t)s * KCL + j) * DIM);
    dst[t] = make_float2(a0, a1);
    if (t == 0) gcnt[s * KCL + j] = (unsigned)n;
}

// ---------------- update: partials -> mean, conv check, commit, ids, resets ----
// grid KCL, block 256. Thread t owns dims 2t, 2t+1 of cluster j.

__global__ __launch_bounds__(256) void k_update(
        float* __restrict__ c,
        const float* __restrict__ gsum, const unsigned* __restrict__ gcnt,
        float* __restrict__ c_sq, unsigned short* __restrict__ ch,
        unsigned long long* __restrict__ packed, int* __restrict__ ids,
        unsigned* __restrict__ viol, const unsigned* __restrict__ done, int it) {
    if (iterDead(done, viol, it)) return;
    int j = blockIdx.x, t = threadIdx.x;
    float a0 = 0.f, a1 = 0.f;
    unsigned cnt = 0;
    #pragma unroll
    for (int s = 0; s < NSLC; ++s) {
        float2 v = ((const float2*)(gsum + ((size_t)s * KCL + j) * DIM))[t];
        a0 += v.x; a1 += v.y;
        cnt += gcnt[s * KCL + j];
    }
    float cf = fmaxf((float)cnt, 1.f);
    float n0 = a0 / cf, n1 = a1 / cf;
    float2 cc = ((const float2*)(c + (size_t)j * DIM))[t];
    bool bad = !((fabsf(cc.x - n0) <= ATOLV + RTOLV * fabsf(n0)) &&
                 (fabsf(cc.y - n1) <= ATOLV + RTOLV * fabsf(n1)));
    unsigned long long bm = __ballot(bad);
    if ((t & 63) == 0 && bm) atomicOr(&viol[it & 1], 1u);
    ((float2*)(c + (size_t)j * DIM))[t] = make_float2(n0, n1);   // commit
    ((unsigned*)(ch + (size_t)j * DIM))[t] =
        (unsigned)bf16rne(n0) | ((unsigned)bf16rne(n1) << 16);
    float ss = blockReduceSum256(n0 * n0 + n1 * n1);
    if (t == 0) c_sq[j] = ss;
    if (t < 32) {                    // extract ids + re-arm packed for next assign
        int i = j * 32 + t;
        ids[i] = (int)(unsigned)(packed[i] & 0xffffffffull);
        packed[i] = ~0ull;
    }
}

// ---------------- loss phase (MFMA path) ----------------

__global__ __launch_bounds__(256) void k_invx(const float* __restrict__ x, float* __restrict__ invx) {
    int r = blockIdx.x, t = threadIdx.x;
    float a = x[(size_t)r * DIM + t], b = x[(size_t)r * DIM + t + 256];
    float s = blockReduceSum256(a * a + b * b);
    if (t == 0) invx[r] = 1.f / ((sqrtf(s) + EPSV) * (TEMPV + EPSV));
}

__global__ __launch_bounds__(256) void k_cn(const float* __restrict__ src, float* __restrict__ cn,
                                            unsigned short* __restrict__ cnh, int do_split) {
    int j = blockIdx.x, t = threadIdx.x;
    float a = src[(size_t)j * DIM + t], b = src[(size_t)j * DIM + t + 256];
    float s = blockReduceSum256(a * a + b * b);
    __shared__ float bc;
    if (t == 0) bc = 1.f / (sqrtf(s) + EPSV);
    __syncthreads();
    float v0 = a * bc, v1 = b * bc;
    cn[(size_t)j * DIM + t] = v0;
    cn[(size_t)j * DIM + t + 256] = v1;
    if (do_split) {
        cnh[(size_t)j * DIM + t] = bf16rne(v0);
        cnh[(size_t)j * DIM + t + 256] = bf16rne(v1);
    }
}

// bf16 MFMA logits with fused per-row (max, expsum) partials per col-block.
__global__ __launch_bounds__(256) void k_logits_mfma(
        const unsigned short* __restrict__ xh,
        const unsigned short* __restrict__ cnh,
        const float* __restrict__ invx,
        float* __restrict__ pmax, float* __restrict__ psum) {
    int tid = threadIdx.x;
    int w = tid >> 6, l = tid & 63;
    int lr = l & 15, lg = l >> 4;
    int row0 = blockIdx.y * 128 + w * 32;
    int col0 = blockIdx.x * 128;
    int jb = blockIdx.x;

    f32x4 acc[2][8];
    #pragma unroll
    for (int rf = 0; rf < 2; ++rf)
        #pragma unroll
        for (int cf = 0; cf < 8; ++cf) acc[rf][cf] = (f32x4){0.f, 0.f, 0.f, 0.f};

    const unsigned short* a0p = xh + (size_t)(row0 + lr) * DIM + 8 * lg;
    const unsigned short* a1p = a0p + (size_t)16 * DIM;
    const unsigned short* bp  = cnh + (size_t)(col0 + lr) * DIM + 8 * lg;

    #pragma unroll 2
    for (int k0 = 0; k0 < DIM; k0 += 32) {
        s16x8 a0 = *reinterpret_cast<const s16x8*>(a0p + k0);
        s16x8 a1 = *reinterpret_cast<const s16x8*>(a1p + k0);
        #pragma unroll
        for (int cf = 0; cf < 8; ++cf) {
            s16x8 b = *reinterpret_cast<const s16x8*>(bp + (size_t)cf * 16 * DIM + k0);
            acc[0][cf] = __builtin_amdgcn_mfma_f32_16x16x32_bf16(a0, b, acc[0][cf], 0, 0, 0);
            acc[1][cf] = __builtin_amdgcn_mfma_f32_16x16x32_bf16(a1, b, acc[1][cf], 0, 0, 0);
        }
    }

    #pragma unroll
    for (int rf = 0; rf < 2; ++rf) {
        #pragma unroll
        for (int r = 0; r < 4; ++r) {
            int row = row0 + rf * 16 + lg * 4 + r;
            float inv = invx[row];
            float m = -3.0e38f;
            #pragma unroll
            for (int cf = 0; cf < 8; ++cf) m = fmaxf(m, acc[rf][cf][r] * inv);
            #pragma unroll
            for (int msk = 1; msk <= 8; msk <<= 1) m = fmaxf(m, __shfl_xor(m, msk, 64));
            float s = 0.f;
            #pragma unroll
            for (int cf = 0; cf < 8; ++cf) s += expf(acc[rf][cf][r] * inv - m);
            #pragma unroll
            for (int msk = 1; msk <= 8; msk <<= 1) s += __shfl_xor(s, msk, 64);
            if (lr == 0) {
                pmax[(size_t)row * 4 + jb] = m;
                psum[(size_t)row * 4 + jb] = s;
            }
        }
    }
}

__global__ __launch_bounds__(256) void k_loss(const float* __restrict__ x,
                                              const float* __restrict__ cn,
                                              const int* __restrict__ ids,
                                              const float* __restrict__ invx,
                                              const float* __restrict__ pmax,
                                              const float* __restrict__ psum,
                                              float* __restrict__ loss) {
    int i = blockIdx.x * 256 + threadIdx.x;
    float M = -1e30f;
    #pragma unroll
    for (int b = 0; b < 4; ++b) M = fmaxf(M, pmax[(size_t)i * 4 + b]);
    float S = 0.f;
    #pragma unroll
    for (int b = 0; b < 4; ++b) S += psum[(size_t)i * 4 + b] * expf(pmax[(size_t)i * 4 + b] - M);
    float lse = M + logf(S);
    int j = ids[i];
    const float4* xr = (const float4*)(x + (size_t)i * DIM);
    const float4* cr = (const float4*)(cn + (size_t)j * DIM);
    float dot = 0.f;
    for (int q = 0; q < 128; ++q) {
        float4 a = xr[q], b = cr[q];
        dot += a.x * b.x + a.y * b.y + a.z * b.z + a.w * b.w;
    }
    float t = dot * invx[i];
    float contrib = lse - t;
    float s = blockReduceSum256(contrib);
    if (threadIdx.x == 0) atomicAdd(loss, s);
}

__global__ void k_final(const float* __restrict__ loss, float* __restrict__ out) {
    out[0] = *loss / (float)NPTS;
}

// ---------------- fallback fp32 path (ws too small) ----------------

__global__ __launch_bounds__(256) void k_assign(const float* __restrict__ x,
                                                const float* __restrict__ ct,
                                                const float* __restrict__ csq,
                                                unsigned long long* __restrict__ packed,
                                                const unsigned* __restrict__ done) {
    if (*done) return;
    __shared__ float As[16][128];
    __shared__ float Bs[16][128];
    __shared__ float redv[128][17];
    __shared__ int   redj[128][17];

    int tid = threadIdx.x;
    int ty = tid >> 4, tx = tid & 15;
    int row0 = blockIdx.x * 128, col0 = blockIdx.y * 128;

    float acc[8][8];
    #pragma unroll
    for (int i = 0; i < 8; ++i)
        #pragma unroll
        for (int j = 0; j < 8; ++j) acc[i][j] = 0.f;

    for (int dk = 0; dk < DIM; dk += 16) {
        {
            int r = tid >> 1;
            int d0 = (tid & 1) * 8;
            const float4* src = reinterpret_cast<const float4*>(&x[(size_t)(row0 + r) * DIM + dk + d0]);
            float4 v0 = src[0], v1 = src[1];
            As[d0 + 0][r] = v0.x; As[d0 + 1][r] = v0.y; As[d0 + 2][r] = v0.z; As[d0 + 3][r] = v0.w;
            As[d0 + 4][r] = v1.x; As[d0 + 5][r] = v1.y; As[d0 + 6][r] = v1.z; As[d0 + 7][r] = v1.w;
        }
        {
            int d = tid >> 4;
            int c0 = (tid & 15) * 8;
            const float4* src = reinterpret_cast<const float4*>(&ct[(size_t)(dk + d) * KCL + col0 + c0]);
            float4 v0 = src[0], v1 = src[1];
            *reinterpret_cast<float4*>(&Bs[d][c0]) = v0;
            *reinterpret_cast<float4*>(&Bs[d][c0 + 4]) = v1;
        }
        __syncthreads();
        #pragma unroll
        for (int kk = 0; kk < 16; ++kk) {
            float a[8], b[8];
            *(float4*)&a[0] = *(const float4*)&As[kk][ty * 8];
            *(float4*)&a[4] = *(const float4*)&As[kk][ty * 8 + 4];
            *(float4*)&b[0] = *(const float4*)&Bs[kk][tx * 8];
            *(float4*)&b[4] = *(const float4*)&Bs[kk][tx * 8 + 4];
            #pragma unroll
            for (int i = 0; i < 8; ++i)
                #pragma unroll
                for (int j = 0; j < 8; ++j) acc[i][j] = fmaf(a[i], b[j], acc[i][j]);
        }
        __syncthreads();
    }

    #pragma unroll
    for (int i = 0; i < 8; ++i) {
        float best = 1e30f; int bj = col0 + tx * 8;
        #pragma unroll
        for (int j = 0; j < 8; ++j) {
            int col = col0 + tx * 8 + j;
            float v = csq[col] - 2.f * acc[i][j];
            if (v < best) { best = v; bj = col; }
        }
        redv[ty * 8 + i][tx] = best;
        redj[ty * 8 + i][tx] = bj;
    }
    __syncthreads();
    if (tid < 128) {
        float best = 1e30f; int bj = 0x7fffffff;
        for (int t2 = 0; t2 < 16; ++t2) {
            float v = redv[tid][t2]; int j = redj[tid][t2];
            if (v < best || (v == best && j < bj)) { best = v; bj = j; }
        }
        unsigned u = __float_as_uint(best);
        u ^= (u >> 31) ? 0xFFFFFFFFu : 0x80000000u;
        unsigned long long key = ((unsigned long long)u << 32) | (unsigned)bj;
        atomicMin(&packed[row0 + tid], key);
    }
}

__global__ __launch_bounds__(256) void k_hist(const unsigned long long* __restrict__ packed,
                                              int* __restrict__ ids, unsigned* __restrict__ counts,
                                              const unsigned* __restrict__ done) {
    if (*done) return;
    int i = blockIdx.x * 256 + threadIdx.x;
    unsigned long long p = packed[i];
    int j = (int)(unsigned)(p & 0xffffffffull);
    ids[i] = j;
    atomicAdd(&counts[j], 1u);
}

__global__ void k_scan(const unsigned* __restrict__ counts, unsigned* __restrict__ offsets,
                       unsigned* __restrict__ cursors, const unsigned* __restrict__ done) {
    if (*done) return;
    __shared__ unsigned s[512];
    int t = threadIdx.x;
    unsigned c0 = counts[t];
    s[t] = c0;
    __syncthreads();
    for (int off = 1; off < 512; off <<= 1) {
        unsigned v = (t >= off) ? s[t - off] : 0u;
        __syncthreads();
        s[t] += v;
        __syncthreads();
    }
    unsigned excl = s[t] - c0;
    offsets[t] = excl;
    cursors[t] = excl;
}

__global__ __launch_bounds__(256) void k_scatter(const int* __restrict__ ids,
                                                 unsigned* __restrict__ cursors,
                                                 int* __restrict__ order,
                                                 const unsigned* __restrict__ done) {
    if (*done) return;
    int i = blockIdx.x * 256 + threadIdx.x;
    int j = ids[i];
    unsigned pos = atomicAdd(&cursors[j], 1u);
    order[pos] = i;
}

__global__ __launch_bounds__(256) void k_sumconv(const float* __restrict__ x,
                                                 const int* __restrict__ order,
                                                 const unsigned* __restrict__ offsets,
                                                 const unsigned* __restrict__ counts,
                                                 const float* __restrict__ c,
                                                 float* __restrict__ new_c,
                                                 unsigned* __restrict__ viol,
                                                 const unsigned* __restrict__ done, int it) {
    if (*done) return;
    int j = blockIdx.x, t = threadIdx.x;
    unsigned cnt = counts[j], base = offsets[j];
    float a0 = 0.f, a1 = 0.f;
    for (unsigned p = 0; p < cnt; ++p) {
        int i = order[base + p];
        const float* xr = x + (size_t)i * DIM;
        a0 += xr[t]; a1 += xr[t + 256];
    }
    float cf = fmaxf((float)cnt, 1.f);
    float n0 = a0 / cf, n1 = a1 / cf;
    new_c[(size_t)j * DIM + t] = n0;
    new_c[(size_t)j * DIM + t + 256] = n1;
    float c0 = c[(size_t)j * DIM + t], c1 = c[(size_t)j * DIM + t + 256];
    bool ok = (fabsf(c0 - n0) <= ATOLV + RTOLV * fabsf(n0)) &&
              (fabsf(c1 - n1) <= ATOLV + RTOLV * fabsf(n1));
    unsigned long long bad = __ballot(!ok);
    if ((t & 63) == 0 && bad) atomicOr(&viol[it & 1], 1u);
}

__global__ __launch_bounds__(256) void k_commit(float* __restrict__ c, const float* __restrict__ new_c,
                                                float* __restrict__ c_sq,
                                                unsigned long long* __restrict__ packed,
                                                unsigned* __restrict__ counts,
                                                unsigned* __restrict__ viol,
                                                unsigned* __restrict__ done, int it) {
    if (*done) return;
    unsigned v = viol[it & 1];
    int b = blockIdx.x, t = threadIdx.x;
    int e = b * 256 + t;
    if (v) {
        float n0 = new_c[(size_t)b * DIM + t], n1 = new_c[(size_t)b * DIM + t + 256];
        c[(size_t)b * DIM + t] = n0;
        c[(size_t)b * DIM + t + 256] = n1;
        float s = blockReduceSum256(n0 * n0 + n1 * n1);
        if (t == 0) c_sq[b] = s;
    } else {
        if (e == 0) *done = 1u;
    }
    if (e < NPTS) packed[e] = ~0ull;
    if (e < KCL) counts[e] = 0u;
    if (e == 0) viol[(it + 1) & 1] = 0u;
}

__global__ void k_trans(const float* __restrict__ src, float* __restrict__ dst,
                        const unsigned* __restrict__ done, int check) {
    if (check && *done) return;
    __shared__ float tile[32][33];
    int bx = blockIdx.x & 15, by = blockIdx.x >> 4;
    int tx = threadIdx.x & 31, ty = threadIdx.x >> 5;
    #pragma unroll
    for (int q = 0; q < 4; ++q) {
        int r = by * 32 + ty + q * 8;
        tile[ty + q * 8][tx] = src[(size_t)r * DIM + bx * 32 + tx];
    }
    __syncthreads();
    #pragma unroll
    for (int q = 0; q < 4; ++q) {
        int d = bx * 32 + ty + q * 8;
        dst[(size_t)d * KCL + by * 32 + tx] = tile[tx][ty + q * 8];
    }
}

__global__ __launch_bounds__(256) void k_logits(const float* __restrict__ x,
                                                const float* __restrict__ ct,
                                                const float* __restrict__ invx,
                                                float* __restrict__ pmax, float* __restrict__ psum) {
    __shared__ float As[16][128];
    __shared__ float Bs[16][128];
    __shared__ float red2[128][17];
    __shared__ float rowm[128];

    int tid = threadIdx.x;
    int ty = tid >> 4, tx = tid & 15;
    int row0 = blockIdx.x * 128, col0 = blockIdx.y * 128;
    int jb = blockIdx.y;

    float acc[8][8];
    #pragma unroll
    for (int i = 0; i < 8; ++i)
        #pragma unroll
        for (int j = 0; j < 8; ++j) acc[i][j] = 0.f;

    for (int dk = 0; dk < DIM; dk += 16) {
        {
            int r = tid >> 1;
            int d0 = (tid & 1) * 8;
            const float4* src = reinterpret_cast<const float4*>(&x[(size_t)(row0 + r) * DIM + dk + d0]);
            float4 v0 = src[0], v1 = src[1];
            As[d0 + 0][r] = v0.x; As[d0 + 1][r] = v0.y; As[d0 + 2][r] = v0.z; As[d0 + 3][r] = v0.w;
            As[d0 + 4][r] = v1.x; As[d0 + 5][r] = v1.y; As[d0 + 6][r] = v1.z; As[d0 + 7][r] = v1.w;
        }
        {
            int d = tid >> 4;
            int c0 = (tid & 15) * 8;
            const float4* src = reinterpret_cast<const float4*>(&ct[(size_t)(dk + d) * KCL + col0 + c0]);
            float4 v0 = src[0], v1 = src[1];
            *reinterpret_cast<float4*>(&Bs[d][c0]) = v0;
            *reinterpret_cast<float4*>(&Bs[d][c0 + 4]) = v1;
        }
        __syncthreads();
        #pragma unroll
        for (int kk = 0; kk < 16; ++kk) {
            float a[8], b[8];
            *(float4*)&a[0] = *(const float4*)&As[kk][ty * 8];
            *(float4*)&a[4] = *(const float4*)&As[kk][ty * 8 + 4];
            *(float4*)&b[0] = *(const float4*)&Bs[kk][tx * 8];
            *(float4*)&b[4] = *(const float4*)&Bs[kk][tx * 8 + 4];
            #pragma unroll
            for (int i = 0; i < 8; ++i)
                #pragma unroll
                for (int j = 0; j < 8; ++j) acc[i][j] = fmaf(a[i], b[j], acc[i][j]);
        }
        __syncthreads();
    }

    float inv[8];
    #pragma unroll
    for (int i = 0; i < 8; ++i) inv[i] = invx[row0 + ty * 8 + i];

    #pragma unroll
    for (int i = 0; i < 8; ++i) {
        float m = -1e30f;
        #pragma unroll
        for (int j = 0; j < 8; ++j) m = fmaxf(m, acc[i][j] * inv[i]);
        red2[ty * 8 + i][tx] = m;
    }
    __syncthreads();
    if (tid < 128) {
        float m = -1e30f;
        for (int t2 = 0; t2 < 16; ++t2) m = fmaxf(m, red2[tid][t2]);
        rowm[tid] = m;
    }
    __syncthreads();
    #pragma unroll
    for (int i = 0; i < 8; ++i) {
        float M = rowm[ty * 8 + i];
        float s = 0.f;
        #pragma unroll
        for (int j = 0; j < 8; ++j) s += expf(acc[i][j] * inv[i] - M);
        red2[ty * 8 + i][tx] = s;
    }
    __syncthreads();
    if (tid < 128) {
        float s = 0.f;
        for (int t2 = 0; t2 < 16; ++t2) s += red2[tid][t2];
        pmax[(size_t)(row0 + tid) * 4 + jb] = rowm[tid];
        psum[(size_t)(row0 + tid) * 4 + jb] = s;
    }
}

// ---------------- launch ----------------

extern "C" void kernel_launch(void* const* d_in, const int* in_sizes, int n_in,
                              void* d_out, int out_size, void* d_ws, size_t ws_size,
                              hipStream_t stream) {
    const float* x = (const float*)d_in[0];
    const int* init_idx = (const int*)d_in[1];
    float* out = (float*)d_out;

    char* w = (char*)d_ws;
    float* c      = (float*)w; w += (size_t)KCL * DIM * 4;
    float* new_c  = (float*)w; w += (size_t)KCL * DIM * 4;
    float* ct     = (float*)w; w += (size_t)DIM * KCL * 4;
    float* c_sq   = (float*)w; w += KCL * 4;
    unsigned* counts  = (unsigned*)w; w += KCL * 4;
    unsigned* offsets = (unsigned*)w; w += KCL * 4;
    unsigned* cursors = (unsigned*)w; w += KCL * 4;
    unsigned* done = (unsigned*)w; w += 64;
    unsigned* viol = (unsigned*)w; w += 64;
    float* loss    = (float*)w; w += 64;
    int* ids   = (int*)w; w += NPTS * 4;
    int* order = (int*)w; w += NPTS * 4;
    unsigned long long* packed = (unsigned long long*)w; w += NPTS * 8;
    float* invx = (float*)w; w += NPTS * 4;
    float* pmax = (float*)w; w += (size_t)NPTS * 4 * 4;
    float* psum = (float*)w; w += (size_t)NPTS * 4 * 4;
    unsigned short* ch = (unsigned short*)w; w += (size_t)KCL * DIM * 2;
    unsigned short* cnh = (unsigned short*)w; w += (size_t)KCL * DIM * 2;
    unsigned short* xh = (unsigned short*)w; w += (size_t)NPTS * DIM * 2;
    float* gsum = (float*)w; w += (size_t)NSLC * KCL * DIM * 4;
    unsigned* gcnt = (unsigned*)w; w += (size_t)NSLC * KCL * 4;
    size_t need = (size_t)(w - (char*)d_ws);
    int use_mfma = (ws_size >= need) ? 1 : 0;

    k_init0<<<1024, 256, 0, stream>>>(x, init_idx, c, ct, ch, packed, counts, done, viol, loss, use_mfma);
    k_csq0<<<KCL, 256, 0, stream>>>(c, c_sq);
    if (use_mfma)
        k_splitx<<<NPTS * DIM / 4 / 256, 256, 0, stream>>>(x, xh);

    for (int it = 0; it < MAXIT; ++it) {
        if (use_mfma) {
            k_assign_mfma<<<dim3(4, 64), 256, 0, stream>>>(xh, ch, c_sq, packed, viol, done, it);
            k_gather<<<dim3(KCL, NSLC), 256, 0, stream>>>(packed, xh, gsum, gcnt, viol, done, it);
            k_update<<<KCL, 256, 0, stream>>>(c, gsum, gcnt, c_sq, ch, packed, ids, viol, done, it);
        } else {
            k_assign<<<dim3(128, 4), 256, 0, stream>>>(x, ct, c_sq, packed, done);
            k_hist<<<64, 256, 0, stream>>>(packed, ids, counts, done);
            k_scan<<<1, 512, 0, stream>>>(counts, offsets, cursors, done);
            k_scatter<<<64, 256, 0, stream>>>(ids, cursors, order, done);
            k_sumconv<<<KCL, 256, 0, stream>>>(x, order, offsets, counts, c, new_c, viol, done, it);
            k_commit<<<KCL, 256, 0, stream>>>(c, new_c, c_sq, packed, counts, viol, done, it);
            k_trans<<<256, 256, 0, stream>>>(new_c, ct, done, 1);
        }
    }

    // loss phase: centers live in c (mfma path) / new_c (fallback)
    k_invx<<<NPTS, 256, 0, stream>>>(x, invx);
    if (use_mfma) {
        k_cn<<<KCL, 256, 0, stream>>>(c, c, cnh, 1);      // in-place normalize c -> cn
        k_logits_mfma<<<dim3(4, 128), 256, 0, stream>>>(xh, cnh, invx, pmax, psum);
    } else {
        k_cn<<<KCL, 256, 0, stream>>>(new_c, c, cnh, 0);
        k_trans<<<256, 256, 0, stream>>>(c, ct, done, 0);
        k_logits<<<dim3(128, 4), 256, 0, stream>>>(x, ct, invx, pmax, psum);
    }
    k_loss<<<64, 256, 0, stream>>>(x, c, ids, invx, pmax, psum, loss);
    k_final<<<1, 1, 0, stream>>>(loss, out);
}